// Round 14
// baseline (239.607 us; speedup 1.0000x reference)
//
#include <hip/hip_runtime.h>

#define NBLK 256

typedef float f2 __attribute__((ext_vector_type(2)));   // VGPR pair -> VOP3P v_pk_* f32
typedef float f4 __attribute__((ext_vector_type(4)));

static __device__ __forceinline__ f2 pk_fma(f2 a, f2 b, f2 c) {
#if __has_builtin(__builtin_elementwise_fma)
    return __builtin_elementwise_fma(a, b, c);
#else
    f2 r; r.x = fmaf(a.x, b.x, c.x); r.y = fmaf(a.y, b.y, c.y); return r;
#endif
}

// packed tanh(z) and 1-tanh^2: tanh = 1 - 2/(exp2(2*log2e*z)+1). abs err ~3e-7.
__device__ __forceinline__ void tanh2(const f2 z, f2& th, f2& om) {
    const f2 zz = z * 2.88539008f;
    f2 s;
    s.x = __builtin_amdgcn_rcpf(__builtin_amdgcn_exp2f(zz.x) + 1.0f);
    s.y = __builtin_amdgcn_rcpf(__builtin_amdgcn_exp2f(zz.y) + 1.0f);
    th = 1.0f - 2.0f * s;
    om = 1.0f - th * th;
}

__global__ __launch_bounds__(NBLK) void pinn_kernel(
    const float* __restrict__ T,
    const float* __restrict__ W1, const float* __restrict__ b1,
    const float* __restrict__ W2, const float* __restrict__ b2,
    const float* __restrict__ W3, const float* __restrict__ b3,
    const float* __restrict__ W4, const float* __restrict__ b4,
    const float* __restrict__ Wo, const float* __restrict__ bo,
    const float* __restrict__ C1, const float* __restrict__ C2, const float* __restrict__ C3,
    float* __restrict__ out, int n)
{
    const int i0 = blockIdx.x * NBLK + threadIdx.x;
    const int i  = (i0 < n) ? i0 : (n - 1);        // clamp load; store guarded below
    const float t = T[i];

    // Laundered zero: compiler can't prove uniformity -> weight loads go to the
    // VMEM pipe (in-order, vmcnt partial waits, deep pipelining) instead of SMEM
    // (out-of-order, full lgkmcnt(0) drain before every use-group = the R7/R11 stall).
    // Same-address-across-lanes loads broadcast from L1 (6.7 KB weight set is L1-hot).
    int vz = 0;
    asm volatile("" : "+v"(vz));

    f2 H[10], D[10];
    const f2 t2 = {t, t};

    // ---- layer 1: z = t*W1 + b1, dz = W1 (tangent dt = 1) ----
    {
        const f4* __restrict__ W1v = reinterpret_cast<const f4*>(W1);
        const f4* __restrict__ b1v = reinterpret_cast<const f4*>(b1);
#pragma unroll
        for (int q = 0; q < 5; ++q) {
            const f4 w4 = W1v[vz + q];
            const f4 b4 = b1v[vz + q];
            const f2 wa = {w4.x, w4.y}, wb = {w4.z, w4.w};
            const f2 ba = {b4.x, b4.y}, bb = {b4.z, b4.w};
            f2 th, om;
            tanh2(pk_fma(t2, wa, ba), th, om);
            H[2*q]   = th;  D[2*q]   = om * wa;
            tanh2(pk_fma(t2, wb, bb), th, om);
            H[2*q+1] = th;  D[2*q+1] = om * wb;
        }
    }

    // ---- layers 2..4: fully inlined (cross-layer load scheduling).
    // Per k: 5x global_load_dwordx4 (rows are 80B = 5 aligned f4) + 20 pk_fma.
#define LAYER(WP, BP) do {                                                      \
        const f4* __restrict__ Wv = reinterpret_cast<const f4*>(WP);            \
        const f4* __restrict__ Bv = reinterpret_cast<const f4*>(BP);            \
        f2 A[10], DD[10];                                                       \
        _Pragma("unroll")                                                       \
        for (int q = 0; q < 5; ++q) {                                           \
            const f4 b4 = Bv[vz + q];                                           \
            A[2*q]    = (f2){b4.x, b4.y};                                       \
            A[2*q+1]  = (f2){b4.z, b4.w};                                       \
            DD[2*q]   = (f2){0.0f, 0.0f};                                       \
            DD[2*q+1] = (f2){0.0f, 0.0f};                                       \
        }                                                                       \
        _Pragma("unroll")                                                       \
        for (int k = 0; k < 20; ++k) {                                          \
            const float hk = (k & 1) ? H[k >> 1].y : H[k >> 1].x;               \
            const float dk = (k & 1) ? D[k >> 1].y : D[k >> 1].x;               \
            const f2 hk2 = {hk, hk};                                            \
            const f2 dk2 = {dk, dk};                                            \
            _Pragma("unroll")                                                   \
            for (int q = 0; q < 5; ++q) {                                       \
                const f4 w4 = Wv[vz + k*5 + q];                                 \
                const f2 wa = {w4.x, w4.y}, wb = {w4.z, w4.w};                  \
                A[2*q]    = pk_fma(hk2, wa, A[2*q]);                            \
                A[2*q+1]  = pk_fma(hk2, wb, A[2*q+1]);                          \
                DD[2*q]   = pk_fma(dk2, wa, DD[2*q]);                           \
                DD[2*q+1] = pk_fma(dk2, wb, DD[2*q+1]);                         \
            }                                                                   \
        }                                                                       \
        _Pragma("unroll")                                                       \
        for (int jj = 0; jj < 10; ++jj) {                                       \
            f2 th, om;                                                          \
            tanh2(A[jj], th, om);                                               \
            H[jj] = th;                                                         \
            D[jj] = om * DD[jj];                                                \
        }                                                                       \
    } while (0)

    LAYER(W2, b2);
    LAYER(W3, b3);
    LAYER(W4, b4);
#undef LAYER

    // ---- output layer: o = h@Wo + bo, go = d@Wo.  Wo loaded once as 15 f4;
    // f2 dot over k-pairs (60 pk_fma instead of 120 fmaf), horizontal add at end.
    f4 WoR[15];
    {
        const f4* __restrict__ Wov = reinterpret_cast<const f4*>(Wo);
#pragma unroll
        for (int m = 0; m < 15; ++m) WoR[m] = Wov[vz + m];
    }
#define WOF(k, j) (((3*(k)+(j)) & 3) == 0 ? WoR[(3*(k)+(j)) >> 2].x : \
                   ((3*(k)+(j)) & 3) == 1 ? WoR[(3*(k)+(j)) >> 2].y : \
                   ((3*(k)+(j)) & 3) == 2 ? WoR[(3*(k)+(j)) >> 2].z : \
                                            WoR[(3*(k)+(j)) >> 2].w)
    f2 o0 = {0,0}, o1 = {0,0}, o2 = {0,0}, g0 = {0,0}, g1 = {0,0}, g2 = {0,0};
#pragma unroll
    for (int kk = 0; kk < 10; ++kk) {
        const f2 hp = H[kk], dp = D[kk];
        const f2 w0 = { WOF(2*kk, 0), WOF(2*kk+1, 0) };
        const f2 w1 = { WOF(2*kk, 1), WOF(2*kk+1, 1) };
        const f2 w2 = { WOF(2*kk, 2), WOF(2*kk+1, 2) };
        o0 = pk_fma(hp, w0, o0);  g0 = pk_fma(dp, w0, g0);
        o1 = pk_fma(hp, w1, o1);  g1 = pk_fma(dp, w1, g1);
        o2 = pk_fma(hp, w2, o2);  g2 = pk_fma(dp, w2, g2);
    }
#undef WOF

    const float x   = o0.x + o0.y + bo[0];
    const float y   = o1.x + o1.y + bo[1];
    const float zz  = o2.x + o2.y + bo[2];
    const float dx  = g0.x + g0.y;
    const float dy  = g1.x + g1.y;
    const float dz  = g2.x + g2.y;
    const float c1 = C1[0], c2 = C2[0], c3 = C3[0];
    const float fx = dx - c1 * (y - x);
    const float fy = dy - x * (c2 - zz) + y;
    const float fz = dz - x * y + c3 * zz;

    if (i0 < n) {
        // 24*i bytes is 8B-aligned -> three float2 stores
        float2* po = reinterpret_cast<float2*>(out + (size_t)i0 * 6);
        po[0] = make_float2(x,  y);
        po[1] = make_float2(zz, fx);
        po[2] = make_float2(fy, fz);
    }
}

extern "C" void kernel_launch(void* const* d_in, const int* in_sizes, int n_in,
                              void* d_out, int out_size, void* d_ws, size_t ws_size,
                              hipStream_t stream) {
    const float* T  = (const float*)d_in[0];
    const float* W1 = (const float*)d_in[1];
    const float* b1 = (const float*)d_in[2];
    const float* W2 = (const float*)d_in[3];
    const float* b2 = (const float*)d_in[4];
    const float* W3 = (const float*)d_in[5];
    const float* b3 = (const float*)d_in[6];
    const float* W4 = (const float*)d_in[7];
    const float* b4 = (const float*)d_in[8];
    const float* Wo = (const float*)d_in[9];
    const float* bo = (const float*)d_in[10];
    const float* C1 = (const float*)d_in[11];
    const float* C2 = (const float*)d_in[12];
    const float* C3 = (const float*)d_in[13];
    float* out = (float*)d_out;

    const int n = in_sizes[0];
    const int blocks = (n + NBLK - 1) / NBLK;
    pinn_kernel<<<blocks, NBLK, 0, stream>>>(T, W1, b1, W2, b2, W3, b3, W4, b4,
                                             Wo, bo, C1, C2, C3, out, n);
}

// Round 15
// 147.418 us; speedup vs baseline: 1.6254x; 1.6254x over previous
//
#include <hip/hip_runtime.h>

#define NBLK 256

typedef float f2 __attribute__((ext_vector_type(2)));   // VGPR pair -> VOP3P v_pk_* f32
typedef float f4 __attribute__((ext_vector_type(4)));

static __device__ __forceinline__ f2 pk_fma(f2 a, f2 b, f2 c) {
#if __has_builtin(__builtin_elementwise_fma)
    return __builtin_elementwise_fma(a, b, c);
#else
    f2 r; r.x = fmaf(a.x, b.x, c.x); r.y = fmaf(a.y, b.y, c.y); return r;
#endif
}

// packed tanh(z) and 1-tanh^2: tanh = 1 - 2/(exp2(2*log2e*z)+1). abs err ~3e-7.
__device__ __forceinline__ void tanh2(const f2 z, f2& th, f2& om) {
    const f2 zz = z * 2.88539008f;
    f2 s;
    s.x = __builtin_amdgcn_rcpf(__builtin_amdgcn_exp2f(zz.x) + 1.0f);
    s.y = __builtin_amdgcn_rcpf(__builtin_amdgcn_exp2f(zz.y) + 1.0f);
    th = 1.0f - 2.0f * s;
    om = 1.0f - th * th;
}

__global__ __launch_bounds__(NBLK) void pinn_kernel(
    const float* __restrict__ T,
    const float* __restrict__ W1, const float* __restrict__ b1,
    const float* __restrict__ W2, const float* __restrict__ b2,
    const float* __restrict__ W3, const float* __restrict__ b3,
    const float* __restrict__ W4, const float* __restrict__ b4,
    const float* __restrict__ Wo, const float* __restrict__ bo,
    const float* __restrict__ C1, const float* __restrict__ C2, const float* __restrict__ C3,
    float* __restrict__ out, int n)
{
    // Weight stream split across the CU's two broadcast pipes:
    //   even-k rows -> uniform pointer deref -> s_load (SMEM/K$ pipe)
    //   odd-k  rows -> LDS ds_read_b128 broadcast (wave-uniform addr, no conflicts)
    // Each pipe carries ~half the 46-53us serial load; both hide under the VALU shadow.
    __shared__ f4 sOdd[3][10][5];        // odd rows k=2r+1 of W2..W4: 2400 B

    {
        const int u = threadIdx.x;
        if (u < 150) {
            const int L = u / 50, rem = u % 50, r = rem / 5, q = rem % 5;
            const float* WPx = (L == 0) ? W2 : (L == 1) ? W3 : W4;
            sOdd[L][r][q] = *reinterpret_cast<const f4*>(WPx + (2 * r + 1) * 20 + 4 * q);
        }
    }
    __syncthreads();

    const int i0 = blockIdx.x * NBLK + threadIdx.x;
    const int i  = (i0 < n) ? i0 : (n - 1);        // clamp load; store guarded below
    const float t = T[i];

    f2 H[10], D[10];
    const f2 t2 = {t, t};

    // ---- layer 1: z = t*W1 + b1, dz = W1 (tangent dt = 1); SMEM (small) ----
#pragma unroll
    for (int jj = 0; jj < 10; ++jj) {
        const f2 w = *reinterpret_cast<const f2*>(W1 + 2 * jj);
        const f2 b = *reinterpret_cast<const f2*>(b1 + 2 * jj);
        f2 th, om;
        tanh2(pk_fma(t2, w, b), th, om);
        H[jj] = th;
        D[jj] = om * w;
    }

    // ---- layers 2..4: k-outer / q-inner; per (k,q) one f4 of weights + 4 pk_fma ----
#define LAYER(LIDX, WP, BP) do {                                                \
        f2 A[10], DD[10];                                                       \
        _Pragma("unroll")                                                       \
        for (int jj = 0; jj < 10; ++jj) {                                       \
            A[jj]  = *reinterpret_cast<const f2*>(BP + 2 * jj);                 \
            DD[jj] = (f2){0.0f, 0.0f};                                          \
        }                                                                       \
        _Pragma("unroll")                                                       \
        for (int k = 0; k < 20; ++k) {                                          \
            const float hk = (k & 1) ? H[k >> 1].y : H[k >> 1].x;               \
            const float dk = (k & 1) ? D[k >> 1].y : D[k >> 1].x;               \
            const f2 hk2 = {hk, hk};                                            \
            const f2 dk2 = {dk, dk};                                            \
            _Pragma("unroll")                                                   \
            for (int q = 0; q < 5; ++q) {                                       \
                const f4 w4 = (k & 1)                                           \
                    ? sOdd[LIDX][k >> 1][q]                                     \
                    : *reinterpret_cast<const f4*>(WP + k * 20 + 4 * q);        \
                const f2 wa = {w4.x, w4.y}, wb = {w4.z, w4.w};                  \
                A[2*q]    = pk_fma(hk2, wa, A[2*q]);                            \
                A[2*q+1]  = pk_fma(hk2, wb, A[2*q+1]);                          \
                DD[2*q]   = pk_fma(dk2, wa, DD[2*q]);                           \
                DD[2*q+1] = pk_fma(dk2, wb, DD[2*q+1]);                         \
            }                                                                   \
        }                                                                       \
        _Pragma("unroll")                                                       \
        for (int jj = 0; jj < 10; ++jj) {                                       \
            f2 th, om;                                                          \
            tanh2(A[jj], th, om);                                               \
            H[jj] = th;                                                         \
            D[jj] = om * DD[jj];                                                \
        }                                                                       \
    } while (0)

    LAYER(0, W2, b2);
    LAYER(1, W3, b3);
    LAYER(2, W4, b4);
#undef LAYER

    // ---- output layer: o = h@Wo + bo, go = d@Wo (SMEM scalar; small) ----
    float o0 = bo[0], o1 = bo[1], o2 = bo[2];
    float g0 = 0.0f, g1 = 0.0f, g2 = 0.0f;
#pragma unroll
    for (int k = 0; k < 20; ++k) {
        const float hk = (k & 1) ? H[k >> 1].y : H[k >> 1].x;
        const float dk = (k & 1) ? D[k >> 1].y : D[k >> 1].x;
        const float w0 = Wo[k * 3 + 0];
        const float w1 = Wo[k * 3 + 1];
        const float w2 = Wo[k * 3 + 2];
        o0 = fmaf(hk, w0, o0);  g0 = fmaf(dk, w0, g0);
        o1 = fmaf(hk, w1, o1);  g1 = fmaf(dk, w1, g1);
        o2 = fmaf(hk, w2, o2);  g2 = fmaf(dk, w2, g2);
    }

    const float x = o0, y = o1, zz = o2;
    const float c1 = C1[0], c2 = C2[0], c3 = C3[0];
    const float fx = g0 - c1 * (y - x);
    const float fy = g1 - x * (c2 - zz) + y;
    const float fz = g2 - x * y + c3 * zz;

    if (i0 < n) {
        // 24*i bytes is 8B-aligned -> three float2 stores
        float2* po = reinterpret_cast<float2*>(out + (size_t)i0 * 6);
        po[0] = make_float2(x,  y);
        po[1] = make_float2(zz, fx);
        po[2] = make_float2(fy, fz);
    }
}

extern "C" void kernel_launch(void* const* d_in, const int* in_sizes, int n_in,
                              void* d_out, int out_size, void* d_ws, size_t ws_size,
                              hipStream_t stream) {
    const float* T  = (const float*)d_in[0];
    const float* W1 = (const float*)d_in[1];
    const float* b1 = (const float*)d_in[2];
    const float* W2 = (const float*)d_in[3];
    const float* b2 = (const float*)d_in[4];
    const float* W3 = (const float*)d_in[5];
    const float* b3 = (const float*)d_in[6];
    const float* W4 = (const float*)d_in[7];
    const float* b4 = (const float*)d_in[8];
    const float* Wo = (const float*)d_in[9];
    const float* bo = (const float*)d_in[10];
    const float* C1 = (const float*)d_in[11];
    const float* C2 = (const float*)d_in[12];
    const float* C3 = (const float*)d_in[13];
    float* out = (float*)d_out;

    const int n = in_sizes[0];
    const int blocks = (n + NBLK - 1) / NBLK;
    pinn_kernel<<<blocks, NBLK, 0, stream>>>(T, W1, b1, W2, b2, W3, b3, W4, b4,
                                             Wo, bo, C1, C2, C3, out, n);
}